// Round 1
// baseline (125.655 us; speedup 1.0000x reference)
//
#include <hip/hip_runtime.h>
#include <cstdint>

#define LN_EPS 1e-12f
#define NTOK 32768
#define HDIM 768
#define DDIM 16
#define MMEM 50

// ws layout (floats)
#define WS_W1   0        // 12288: g1-folded W_down
#define WS_G    12288    // 16
#define WS_C    12304    // 16 (includes b_down)
#define WS_KEY  12320    // 800
#define WS_VAL  13120    // 800
#define WS_R    16384    // 32768*16

__global__ __launch_bounds__(256) void pre_kernel(
    const float* __restrict__ g1, const float* __restrict__ b1,
    const float* __restrict__ W_down, const float* __restrict__ b_down,
    const float* __restrict__ memory, const float* __restrict__ W_k,
    const float* __restrict__ b_k, const float* __restrict__ W_v,
    const float* __restrict__ b_v, float* __restrict__ ws)
{
    const int tid = threadIdx.x;
    // W1 = diag(g1) @ W_down
    const float4* Wd4 = (const float4*)W_down;
    float4* W14 = (float4*)(ws + WS_W1);
    for (int e = tid; e < (HDIM*DDIM)/4; e += 256) {
        const int i = e >> 2;
        float4 w = Wd4[e];
        const float s = g1[i];
        w.x *= s; w.y *= s; w.z *= s; w.w *= s;
        W14[e] = w;
    }
    // G[k] = sum_i g1[i]*Wd[i,k];  C[k] = sum_i b1[i]*Wd[i,k] + b_down[k]
    __shared__ float redG[16][17];
    __shared__ float redC[16][17];
    const int k = tid & 15, g = tid >> 4;
    float pG = 0.f, pC = 0.f;
    for (int i = g*(HDIM/16); i < (g+1)*(HDIM/16); ++i) {
        const float w = W_down[i*DDIM + k];
        pG = fmaf(g1[i], w, pG);
        pC = fmaf(b1[i], w, pC);
    }
    redG[g][k] = pG; redC[g][k] = pC;
    __syncthreads();
    if (tid < 16) {
        float sG = 0.f, sC = 0.f;
        for (int gg = 0; gg < 16; ++gg) { sG += redG[gg][tid]; sC += redC[gg][tid]; }
        ws[WS_G + tid] = sG;
        ws[WS_C + tid] = sC + b_down[tid];
    }
    // key = memory@W_k + b_k ; val = memory@W_v + b_v
    for (int e = tid; e < MMEM*DDIM; e += 256) {
        const int m = e >> 4, kk = e & 15;
        float sk = b_k[kk], sv = b_v[kk];
        for (int dd = 0; dd < DDIM; ++dd) {
            const float mv = memory[m*DDIM + dd];
            sk = fmaf(mv, W_k[dd*DDIM + kk], sk);
            sv = fmaf(mv, W_v[dd*DDIM + kk], sv);
        }
        ws[WS_KEY + e] = sk;
        ws[WS_VAL + e] = sv;
    }
}

#define ACC1(XU, I0)                                                    \
    {                                                                   \
        const float xu_ = (XU);                                         \
        S0 += xu_; S1 = fmaf(xu_, xu_, S1);                             \
        const int ii_ = (I0);                                           \
        _Pragma("unroll")                                               \
        for (int kq = 0; kq < 4; ++kq) {                                \
            const float4 w = W14[ii_*4 + kq];                           \
            A[kq*4+0] = fmaf(xu_, w.x, A[kq*4+0]);                      \
            A[kq*4+1] = fmaf(xu_, w.y, A[kq*4+1]);                      \
            A[kq*4+2] = fmaf(xu_, w.z, A[kq*4+2]);                      \
            A[kq*4+3] = fmaf(xu_, w.w, A[kq*4+3]);                      \
        }                                                               \
    }

__global__ __launch_bounds__(64) void down_kernel(
    const float* __restrict__ x,
    const float* __restrict__ wsc,
    const float* __restrict__ g2, const float* __restrict__ b2,
    const float* __restrict__ g3, const float* __restrict__ b3,
    float* __restrict__ ws_r)
{
    const int lane = threadIdx.x;
    const int tok = blockIdx.x * 64 + lane;
    const float4* __restrict__ xr = (const float4*)(x + (size_t)tok * HDIM);
    const float4* __restrict__ W14 = (const float4*)(wsc + WS_W1);

    float A[16];
#pragma unroll
    for (int k = 0; k < 16; ++k) A[k] = 0.f;
    float S0 = 0.f, S1 = 0.f;

#pragma unroll 2
    for (int ib = 0; ib < HDIM/16; ++ib) {
#pragma unroll
        for (int q = 0; q < 4; ++q) {
            const float4 xv = xr[ib*4 + q];
            const int i0 = ib*16 + q*4;
            ACC1(xv.x, i0+0)
            ACC1(xv.y, i0+1)
            ACC1(xv.z, i0+2)
            ACC1(xv.w, i0+3)
        }
    }

    // LN1 (folded) -> d
    const float inv_h = 1.0f / 768.0f;
    const float mean1 = S0 * inv_h;
    const float var1 = fmaf(-mean1, mean1, S1 * inv_h);
    const float rs1 = rsqrtf(var1 + LN_EPS);
    float d[16];
#pragma unroll
    for (int k = 0; k < 16; ++k)
        d[k] = fmaf(rs1, fmaf(-mean1, wsc[WS_G + k], A[k]), wsc[WS_C + k]);

    // LN2 -> q
    float t0 = 0.f;
#pragma unroll
    for (int k = 0; k < 16; ++k) t0 += d[k];
    const float mean2 = t0 * 0.0625f;
    float t1 = 0.f;
#pragma unroll
    for (int k = 0; k < 16; ++k) { const float c = d[k] - mean2; t1 = fmaf(c, c, t1); }
    const float rs2 = rsqrtf(t1 * 0.0625f + LN_EPS);
    float qv[16];
#pragma unroll
    for (int k = 0; k < 16; ++k)
        qv[k] = fmaf((d[k] - mean2) * rs2, g2[k], b2[k]);

    // scores + softmax
    const float* __restrict__ KEY = wsc + WS_KEY;
    const float* __restrict__ VAL = wsc + WS_VAL;
    float sc[MMEM];
    float smax = -3.4e38f;
#pragma unroll
    for (int mm = 0; mm < MMEM; ++mm) {
        float a = 0.f;
#pragma unroll
        for (int k = 0; k < 16; ++k) a = fmaf(qv[k], KEY[mm*16 + k], a);
        sc[mm] = a;
        smax = fmaxf(smax, a);
    }
    float ssum = 0.f;
#pragma unroll
    for (int mm = 0; mm < MMEM; ++mm) {
        const float e = __expf(sc[mm] - smax);
        sc[mm] = e;
        ssum += e;
    }
    const float rn = 1.0f / ssum;

    // mem_out = p @ val
    float mo[16];
#pragma unroll
    for (int k = 0; k < 16; ++k) {
        float a = 0.f;
#pragma unroll
        for (int mm = 0; mm < MMEM; ++mm) a = fmaf(sc[mm], VAL[mm*16 + k], a);
        mo[k] = a * rn;
    }

    // LN3 -> r, store
    float u0 = 0.f;
#pragma unroll
    for (int k = 0; k < 16; ++k) u0 += mo[k];
    const float mean3 = u0 * 0.0625f;
    float u1 = 0.f;
#pragma unroll
    for (int k = 0; k < 16; ++k) { const float c = mo[k] - mean3; u1 = fmaf(c, c, u1); }
    const float rs3 = rsqrtf(u1 * 0.0625f + LN_EPS);

    float4* rw = (float4*)(ws_r + (size_t)tok * 16);
#pragma unroll
    for (int q2 = 0; q2 < 4; ++q2) {
        float4 st;
        st.x = fmaf((mo[q2*4+0] - mean3) * rs3, g3[q2*4+0], b3[q2*4+0]);
        st.y = fmaf((mo[q2*4+1] - mean3) * rs3, g3[q2*4+1], b3[q2*4+1]);
        st.z = fmaf((mo[q2*4+2] - mean3) * rs3, g3[q2*4+2], b3[q2*4+2]);
        st.w = fmaf((mo[q2*4+3] - mean3) * rs3, g3[q2*4+3], b3[q2*4+3]);
        rw[q2] = st;
    }
}

__global__ __launch_bounds__(256) void up_kernel(
    const float* __restrict__ ws_r, const float* __restrict__ W_up,
    const float* __restrict__ b_up, float* __restrict__ out)
{
    const int lane = threadIdx.x & 63;
    const int wid = __builtin_amdgcn_readfirstlane(threadIdx.x >> 6);
    const int wg = blockIdx.x * 4 + wid;     // 0..3071
    const int jg = wg % 3;                    // 3 j-groups of 256 columns
    const int tc = wg / 3;                    // 1024 token chunks of 32
    const int j0 = jg * 256 + lane * 4;

    float4 w[16];
#pragma unroll
    for (int k = 0; k < 16; ++k)
        w[k] = *(const float4*)(W_up + k*HDIM + j0);
    const float4 bu = *(const float4*)(b_up + j0);

    const int t0 = tc * 32;
#pragma unroll 2
    for (int tt = 0; tt < 32; ++tt) {
        const int t = t0 + tt;
        const float* __restrict__ rt = ws_r + (size_t)t * 16;
        float4 acc = bu;
#pragma unroll
        for (int k = 0; k < 16; ++k) {
            const float rk = rt[k];
            acc.x = fmaf(rk, w[k].x, acc.x);
            acc.y = fmaf(rk, w[k].y, acc.y);
            acc.z = fmaf(rk, w[k].z, acc.z);
            acc.w = fmaf(rk, w[k].w, acc.w);
        }
        *(float4*)(out + (size_t)t * HDIM + j0) = acc;
    }
}

extern "C" void kernel_launch(void* const* d_in, const int* in_sizes, int n_in,
                              void* d_out, int out_size, void* d_ws, size_t ws_size,
                              hipStream_t stream) {
    const float* x      = (const float*)d_in[0];
    const float* g1     = (const float*)d_in[1];
    const float* b1     = (const float*)d_in[2];
    const float* W_down = (const float*)d_in[3];
    const float* b_down = (const float*)d_in[4];
    const float* g2     = (const float*)d_in[5];
    const float* b2     = (const float*)d_in[6];
    const float* memory = (const float*)d_in[7];
    const float* W_k    = (const float*)d_in[8];
    const float* b_k    = (const float*)d_in[9];
    const float* W_v    = (const float*)d_in[10];
    const float* b_v    = (const float*)d_in[11];
    const float* g3     = (const float*)d_in[12];
    const float* b3     = (const float*)d_in[13];
    const float* W_up   = (const float*)d_in[14];
    const float* b_up   = (const float*)d_in[15];
    float* out = (float*)d_out;
    float* ws  = (float*)d_ws;

    hipLaunchKernelGGL(pre_kernel, dim3(1), dim3(256), 0, stream,
                       g1, b1, W_down, b_down, memory, W_k, b_k, W_v, b_v, ws);
    hipLaunchKernelGGL(down_kernel, dim3(NTOK/64), dim3(64), 0, stream,
                       x, ws, g2, b2, g3, b3, ws + WS_R);
    hipLaunchKernelGGL(up_kernel, dim3(768), dim3(256), 0, stream,
                       ws + WS_R, W_up, b_up, out);
}